// Round 1
// baseline (1031.816 us; speedup 1.0000x reference)
//
#include <hip/hip_runtime.h>
#include <math.h>

// Performer FAVOR+ fast attention — fp32 baseline (round 1).
// B=4 H=16 N=4096 D=64 M=266.
//
// Pipeline:
//  K1 k_pass  : per (bh, 512-row chunk): dd = DNORM*(k@proj^T); accumulate
//               A0[m][e] = sum_n exp(dd-diag)*v[n][e], S0[m] = sum_n exp(dd-diag),
//               Vs[e] = sum_n v[n][e]; gmax[bh] = max(dd) via encoded atomicMax.
//               (No max pre-subtraction needed: exp(dd-diag) <= ~e^20, fp32-safe;
//                the global max is applied later as an exact e^{-mx} scale.)
//  K2 reduce  : ctx[bh][m][0..63] = ratio*(e^{-mx}*A0 + eps*Vs)      (context)
//               ctx[bh][m][64]    = ratio*(e^{-mx}*S0 + eps*N)       (k_cumsum)
//  K3 q_pass  : per (bh, 32-row tile): dd_q, per-row max, qp = exp(dd-diag-mx)+eps
//               (ratio dropped - cancels in num/den), out = (qp@ctx) / (qp@kc).
//
// Workspace: ~41.1 MB of d_ws.

#define BH     64
#define NTOK   4096
#define DIM    64
#define MF     266
#define MT     320      // 5 feature tiles of 64 (padded)
#define MP     272      // 16*17 ownership padding for partial-sum buffers
#define NCH    8
#define CHROWS 512
#define SUB    32
#define RATIO  0.06131393394849658f   // 266^-0.5
#define DNORM  0.35355339059327373f   // 64^-0.25
#define DIAGC  0.0625f                // 0.5 * 64^-0.5
#define KEPS   1e-4f

__device__ __forceinline__ unsigned int encf(float f) {
    unsigned int u = __float_as_uint(f);
    return (u & 0x80000000u) ? ~u : (u | 0x80000000u);
}
__device__ __forceinline__ float decf(unsigned int u) {
    u = (u & 0x80000000u) ? (u & 0x7FFFFFFFu) : ~u;
    return __uint_as_float(u);
}

__global__ __launch_bounds__(256, 2)
void k_pass(const float* __restrict__ kin, const float* __restrict__ vin,
            const float* __restrict__ proj, float* __restrict__ A0p,
            float* __restrict__ S0p, float* __restrict__ Vsp,
            unsigned int* __restrict__ gmax)
{
    __shared__ __align__(16) float ktile[SUB][68];
    __shared__ __align__(16) float vtile[SUB][68];
    __shared__ __align__(16) float pT[64][68];        // transposed proj tile [d][f]
    __shared__ __align__(16) float etile[SUB][MT + 4];// exp(dd - diag), stride 324
    __shared__ float diag[SUB];
    __shared__ float red[256];

    const int tid = threadIdx.x;
    const int bh  = blockIdx.x >> 3;
    const int ch  = blockIdx.x & 7;
    const int tx  = tid & 15;
    const int ty  = tid >> 4;

    const float* kb = kin + ((size_t)bh * NTOK + (size_t)ch * CHROWS) * DIM;
    const float* vb = vin + ((size_t)bh * NTOK + (size_t)ch * CHROWS) * DIM;

    float c0[17][4];
    #pragma unroll
    for (int i = 0; i < 17; ++i) { c0[i][0] = 0.f; c0[i][1] = 0.f; c0[i][2] = 0.f; c0[i][3] = 0.f; }
    float s0a = 0.f, s0b = 0.f, vs = 0.f;
    float dmax = -3.0e38f;

    for (int sub = 0; sub < CHROWS / SUB; ++sub) {
        {   // stage k,v (32x64 each), coalesced float4
            const int r  = tid >> 3;
            const int d0 = (tid & 7) * 8;
            const float4* ks = reinterpret_cast<const float4*>(kb + ((size_t)(sub * SUB + r)) * DIM + d0);
            float4 a = ks[0], b = ks[1];
            *reinterpret_cast<float4*>(&ktile[r][d0])     = a;
            *reinterpret_cast<float4*>(&ktile[r][d0 + 4]) = b;
            const float4* vsrc = reinterpret_cast<const float4*>(vb + ((size_t)(sub * SUB + r)) * DIM + d0);
            float4 c = vsrc[0], d = vsrc[1];
            *reinterpret_cast<float4*>(&vtile[r][d0])     = c;
            *reinterpret_cast<float4*>(&vtile[r][d0 + 4]) = d;
        }
        __syncthreads();
        if (tid < SUB) {
            float s = 0.f;
            #pragma unroll
            for (int d = 0; d < DIM; ++d) { float x = ktile[tid][d]; s += x * x; }
            diag[tid] = s * DIAGC;
        }
        for (int mt = 0; mt < 5; ++mt) {
            __syncthreads();   // pT free; also orders diag on mt==0
            {   // stage transposed proj tile (zeros for f >= 266)
                const int fl = tid >> 2;
                const int d0 = (tid & 3) * 16;
                const int f  = mt * 64 + fl;
                if (f < MF) {
                    const float4* ps = reinterpret_cast<const float4*>(proj + (size_t)f * DIM + d0);
                    #pragma unroll
                    for (int g = 0; g < 4; ++g) {
                        float4 p = ps[g];
                        pT[d0 + g * 4 + 0][fl] = p.x;
                        pT[d0 + g * 4 + 1][fl] = p.y;
                        pT[d0 + g * 4 + 2][fl] = p.z;
                        pT[d0 + g * 4 + 3][fl] = p.w;
                    }
                } else {
                    #pragma unroll
                    for (int g = 0; g < 16; ++g) pT[d0 + g][fl] = 0.f;
                }
            }
            __syncthreads();
            {   // dd for rows (r0, r0+1) x feats (f0..f0+3)
                const int r0 = 2 * ty;
                const int f0 = 4 * tx;
                float acc[2][4] = {{0.f,0.f,0.f,0.f},{0.f,0.f,0.f,0.f}};
                #pragma unroll
                for (int d4 = 0; d4 < 16; ++d4) {
                    float4 ka  = *reinterpret_cast<const float4*>(&ktile[r0][d4 * 4]);
                    float4 ka2 = *reinterpret_cast<const float4*>(&ktile[r0 + 1][d4 * 4]);
                    float a0[4] = {ka.x, ka.y, ka.z, ka.w};
                    float a1[4] = {ka2.x, ka2.y, ka2.z, ka2.w};
                    #pragma unroll
                    for (int dj = 0; dj < 4; ++dj) {
                        float4 pv = *reinterpret_cast<const float4*>(&pT[d4 * 4 + dj][f0]);
                        acc[0][0] += a0[dj] * pv.x; acc[0][1] += a0[dj] * pv.y;
                        acc[0][2] += a0[dj] * pv.z; acc[0][3] += a0[dj] * pv.w;
                        acc[1][0] += a1[dj] * pv.x; acc[1][1] += a1[dj] * pv.y;
                        acc[1][2] += a1[dj] * pv.z; acc[1][3] += a1[dj] * pv.w;
                    }
                }
                const int fb = mt * 64 + f0;
                #pragma unroll
                for (int rr = 0; rr < 2; ++rr) {
                    const float dg = diag[r0 + rr];
                    float dd0 = DNORM * acc[rr][0], dd1 = DNORM * acc[rr][1];
                    float dd2 = DNORM * acc[rr][2], dd3 = DNORM * acc[rr][3];
                    if (fb + 0 < MF) dmax = fmaxf(dmax, dd0);
                    if (fb + 1 < MF) dmax = fmaxf(dmax, dd1);
                    if (fb + 2 < MF) dmax = fmaxf(dmax, dd2);
                    if (fb + 3 < MF) dmax = fmaxf(dmax, dd3);
                    float4 ev;
                    ev.x = __expf(dd0 - dg); ev.y = __expf(dd1 - dg);
                    ev.z = __expf(dd2 - dg); ev.w = __expf(dd3 - dg);
                    *reinterpret_cast<float4*>(&etile[r0 + rr][fb]) = ev;
                }
            }
        }
        __syncthreads();   // etile complete
        {   // C0 += etile^T @ vtile   (m = i*16+ty strided, e = 4*tx..+3)
            #pragma unroll 2
            for (int n = 0; n < SUB; ++n) {
                float4 vv = *reinterpret_cast<const float4*>(&vtile[n][4 * tx]);
                #pragma unroll
                for (int i = 0; i < 17; ++i) {
                    float ev = etile[n][i * 16 + ty];
                    c0[i][0] += ev * vv.x; c0[i][1] += ev * vv.y;
                    c0[i][2] += ev * vv.z; c0[i][3] += ev * vv.w;
                }
            }
        }
        {   // S0 (column sums of etile) and raw-v sums
            #pragma unroll 4
            for (int n = 0; n < SUB; ++n) s0a += etile[n][tid];
            if (tid < MP - 256) {
                #pragma unroll 4
                for (int n = 0; n < SUB; ++n) s0b += etile[n][256 + tid];
            }
            if (tid < 64) {
                #pragma unroll 4
                for (int n = 0; n < SUB; ++n) vs += vtile[n][tid];
            }
        }
        __syncthreads();   // protect tiles before restage
    }

    {   // write partials
        float* dst = A0p + (size_t)(bh * NCH + ch) * MP * 64;
        #pragma unroll
        for (int i = 0; i < 17; ++i) {
            const int m = i * 16 + ty;
            float4 w = make_float4(c0[i][0], c0[i][1], c0[i][2], c0[i][3]);
            *reinterpret_cast<float4*>(dst + (size_t)m * 64 + 4 * tx) = w;
        }
        float* s0d = S0p + (size_t)(bh * NCH + ch) * MP;
        s0d[tid] = s0a;
        if (tid < MP - 256) s0d[256 + tid] = s0b;
        if (tid < 64) Vsp[(size_t)(bh * NCH + ch) * 64 + tid] = vs;
    }
    red[tid] = dmax;
    __syncthreads();
    for (int s = 128; s > 0; s >>= 1) {
        if (tid < s) red[tid] = fmaxf(red[tid], red[tid + s]);
        __syncthreads();
    }
    if (tid == 0) atomicMax(&gmax[bh], encf(red[0]));
}

__global__ void reduce_ctx(const float* __restrict__ A0p, const float* __restrict__ S0p,
                           const float* __restrict__ Vsp, const unsigned int* __restrict__ gmax,
                           float* __restrict__ ctx)
{
    const int bh  = blockIdx.x;
    const int tid = threadIdx.x;
    __shared__ float vst[64];
    if (tid < 64) {
        float s = 0.f;
        for (int c2 = 0; c2 < NCH; ++c2) s += Vsp[(size_t)(bh * NCH + c2) * 64 + tid];
        vst[tid] = s;
    }
    __syncthreads();
    const float mx  = decf(gmax[bh]);
    const float emx = __expf(-mx);
    for (int idx = tid; idx < MP * 68; idx += 256) {
        const int m = idx / 68;
        const int c = idx - m * 68;
        float val = 0.f;
        if (m < MF) {
            if (c < 64) {
                float s = 0.f;
                for (int c2 = 0; c2 < NCH; ++c2)
                    s += A0p[((size_t)(bh * NCH + c2) * MP + m) * 64 + c];
                val = RATIO * (emx * s + KEPS * vst[c]);
            } else if (c == 64) {
                float s = 0.f;
                for (int c2 = 0; c2 < NCH; ++c2)
                    s += S0p[(size_t)(bh * NCH + c2) * MP + m];
                val = RATIO * (emx * s + KEPS * (float)NTOK);
            }
        }
        ctx[(size_t)bh * MP * 68 + idx] = val;
    }
}

__global__ __launch_bounds__(256, 2)
void q_pass(const float* __restrict__ qin, const float* __restrict__ proj,
            const float* __restrict__ ctx, float* __restrict__ outp)
{
    __shared__ __align__(16) float qtile[SUB][68];
    __shared__ __align__(16) float sB[64][68];         // proj^T tile, then ctx tile
    __shared__ __align__(16) float ddt[SUB][MT + 4];
    __shared__ float diag[SUB];
    __shared__ float mxrow[SUB];
    __shared__ float mparts[8][SUB];

    const int tid  = threadIdx.x;
    const int bh   = blockIdx.x >> 7;
    const int tile = blockIdx.x & 127;
    const int tx = tid & 15, ty = tid >> 4;

    const float* qb = qin + ((size_t)bh * NTOK + (size_t)tile * SUB) * DIM;
    const float* cb = ctx + (size_t)bh * MP * 68;
    float* ob = outp + ((size_t)bh * NTOK + (size_t)tile * SUB) * DIM;

    {   // stage q
        const int r  = tid >> 3;
        const int d0 = (tid & 7) * 8;
        const float4* qs = reinterpret_cast<const float4*>(qb + (size_t)r * DIM + d0);
        float4 a = qs[0], b = qs[1];
        *reinterpret_cast<float4*>(&qtile[r][d0])     = a;
        *reinterpret_cast<float4*>(&qtile[r][d0 + 4]) = b;
    }
    __syncthreads();
    if (tid < SUB) {
        float s = 0.f;
        #pragma unroll
        for (int d = 0; d < DIM; ++d) { float x = qtile[tid][d]; s += x * x; }
        diag[tid] = s * DIAGC;
    }
    for (int mt = 0; mt < 5; ++mt) {
        __syncthreads();
        {   // stage transposed proj tile
            const int fl = tid >> 2;
            const int d0 = (tid & 3) * 16;
            const int f  = mt * 64 + fl;
            if (f < MF) {
                const float4* ps = reinterpret_cast<const float4*>(proj + (size_t)f * DIM + d0);
                #pragma unroll
                for (int g = 0; g < 4; ++g) {
                    float4 p = ps[g];
                    sB[d0 + g * 4 + 0][fl] = p.x;
                    sB[d0 + g * 4 + 1][fl] = p.y;
                    sB[d0 + g * 4 + 2][fl] = p.z;
                    sB[d0 + g * 4 + 3][fl] = p.w;
                }
            } else {
                #pragma unroll
                for (int g = 0; g < 16; ++g) sB[d0 + g][fl] = 0.f;
            }
        }
        __syncthreads();
        {
            const int r0 = 2 * ty, f0 = 4 * tx;
            float acc[2][4] = {{0.f,0.f,0.f,0.f},{0.f,0.f,0.f,0.f}};
            #pragma unroll
            for (int d4 = 0; d4 < 16; ++d4) {
                float4 ka  = *reinterpret_cast<const float4*>(&qtile[r0][d4 * 4]);
                float4 ka2 = *reinterpret_cast<const float4*>(&qtile[r0 + 1][d4 * 4]);
                float a0[4] = {ka.x, ka.y, ka.z, ka.w};
                float a1[4] = {ka2.x, ka2.y, ka2.z, ka2.w};
                #pragma unroll
                for (int dj = 0; dj < 4; ++dj) {
                    float4 pv = *reinterpret_cast<const float4*>(&sB[d4 * 4 + dj][f0]);
                    acc[0][0] += a0[dj] * pv.x; acc[0][1] += a0[dj] * pv.y;
                    acc[0][2] += a0[dj] * pv.z; acc[0][3] += a0[dj] * pv.w;
                    acc[1][0] += a1[dj] * pv.x; acc[1][1] += a1[dj] * pv.y;
                    acc[1][2] += a1[dj] * pv.z; acc[1][3] += a1[dj] * pv.w;
                }
            }
            const int fb = mt * 64 + f0;
            #pragma unroll
            for (int rr = 0; rr < 2; ++rr) {
                float4 w;
                w.x = DNORM * acc[rr][0]; w.y = DNORM * acc[rr][1];
                w.z = DNORM * acc[rr][2]; w.w = DNORM * acc[rr][3];
                *reinterpret_cast<float4*>(&ddt[r0 + rr][fb]) = w;
            }
        }
    }
    __syncthreads();
    {   // per-row max over m < MF
        const int row = tid & 31, part = tid >> 5;
        float m = -3.0e38f;
        const int m0 = part * 34;
        const int m1 = (m0 + 34 < MF) ? (m0 + 34) : MF;
        for (int mm = m0; mm < m1; ++mm) m = fmaxf(m, ddt[row][mm]);
        mparts[part][row] = m;
    }
    __syncthreads();
    if (tid < SUB) {
        float m = mparts[0][tid];
        #pragma unroll
        for (int p = 1; p < 8; ++p) m = fmaxf(m, mparts[p][tid]);
        mxrow[tid] = m;
    }
    __syncthreads();
    for (int idx = tid; idx < SUB * MT; idx += 256) {
        const int n = idx / MT;
        const int m = idx - n * MT;
        float v2 = 0.f;
        if (m < MF) v2 = __expf(ddt[n][m] - diag[n] - mxrow[n]) + KEPS;
        ddt[n][m] = v2;
    }
    // out = qp @ ctx_ext, normalized by D = qp @ k_cumsum
    float acc[2][4] = {{0.f,0.f,0.f,0.f},{0.f,0.f,0.f,0.f}};
    float dacc[2] = {0.f, 0.f};
    const int r0 = 2 * ty;
    for (int mc = 0; mc < 5; ++mc) {
        const int rows = (mc == 4) ? (MP - 256) : 64;
        __syncthreads();   // also orders qp-overwrite before gemm reads (mc==0)
        for (int fid = tid; fid < rows * 17; fid += 256) {
            const int r = fid / 17;
            const int c = (fid - r * 17) * 4;
            *reinterpret_cast<float4*>(&sB[r][c]) =
                *reinterpret_cast<const float4*>(cb + (size_t)(mc * 64 + r) * 68 + c);
        }
        __syncthreads();
        #pragma unroll 2
        for (int ml = 0; ml < rows; ++ml) {
            const int m = mc * 64 + ml;
            const float q0 = ddt[r0][m];
            const float q1 = ddt[r0 + 1][m];
            float4 c4 = *reinterpret_cast<const float4*>(&sB[ml][4 * tx]);
            const float kc = sB[ml][64];
            acc[0][0] += q0 * c4.x; acc[0][1] += q0 * c4.y;
            acc[0][2] += q0 * c4.z; acc[0][3] += q0 * c4.w;
            acc[1][0] += q1 * c4.x; acc[1][1] += q1 * c4.y;
            acc[1][2] += q1 * c4.z; acc[1][3] += q1 * c4.w;
            dacc[0] += q0 * kc; dacc[1] += q1 * kc;
        }
    }
    float d0 = (dacc[0] == 0.f) ? 1e-5f : dacc[0];
    float d1 = (dacc[1] == 0.f) ? 1e-5f : dacc[1];
    const float i0 = 1.0f / d0, i1 = 1.0f / d1;
    float4 o0 = make_float4(acc[0][0] * i0, acc[0][1] * i0, acc[0][2] * i0, acc[0][3] * i0);
    float4 o1 = make_float4(acc[1][0] * i1, acc[1][1] * i1, acc[1][2] * i1, acc[1][3] * i1);
    *reinterpret_cast<float4*>(ob + (size_t)r0 * DIM + 4 * tx)       = o0;
    *reinterpret_cast<float4*>(ob + (size_t)(r0 + 1) * DIM + 4 * tx) = o1;
}

extern "C" void kernel_launch(void* const* d_in, const int* in_sizes, int n_in,
                              void* d_out, int out_size, void* d_ws, size_t ws_size,
                              hipStream_t stream)
{
    const float* q    = (const float*)d_in[0];
    const float* k    = (const float*)d_in[1];
    const float* v    = (const float*)d_in[2];
    const float* proj = (const float*)d_in[3];
    float* out = (float*)d_out;
    float* ws  = (float*)d_ws;

    const size_t offA = 0;
    const size_t offS = offA + (size_t)BH * NCH * MP * 64;   // A0 partials
    const size_t offV = offS + (size_t)BH * NCH * MP;        // S0 partials
    const size_t offG = offV + (size_t)BH * NCH * 64;        // Vs partials
    const size_t offC = offG + 64;                           // gmax (encoded uint)
    // total floats = offC + BH*MP*68 = 10,268,736  (~41.1 MB of d_ws)

    float* A0p = ws + offA;
    float* S0p = ws + offS;
    float* Vsp = ws + offV;
    unsigned int* gmax = (unsigned int*)(ws + offG);
    float* ctx = ws + offC;

    hipMemsetAsync(gmax, 0, 64 * sizeof(unsigned int), stream);
    hipLaunchKernelGGL(k_pass, dim3(BH * NCH), dim3(256), 0, stream,
                       k, v, proj, A0p, S0p, Vsp, gmax);
    hipLaunchKernelGGL(reduce_ctx, dim3(BH), dim3(256), 0, stream,
                       A0p, S0p, Vsp, gmax, ctx);
    hipLaunchKernelGGL(q_pass, dim3(BH * 128), dim3(256), 0, stream,
                       q, proj, ctx, out);
}

// Round 2
// 184.013 us; speedup vs baseline: 5.6073x; 5.6073x over previous
//
#include <hip/hip_runtime.h>
#include <math.h>

// Performer FAVOR+ fast attention — MFMA version (round 2).
// B=4 H=16 N=4096 D=64 M=266.
// GEMM1 (x@projT) in f16 MFMA, k-side GEMM2 in bf16 (range), q-side GEMM2 in f16.

#define BH 64
#define NTOK 4096
#define DIM 64
#define MF 266
#define MPAD 272
#define NCH 8
#define CHROWS 512
#define RATIO 0.06131393394849658f   // 266^-0.5
#define DNORM 0.35355339059327373f   // 64^-0.25
#define DIAGC 0.0625f                // 0.5 * 64^-0.5
#define KEPS 1e-4f

#define PSTR 72     // proj/epT/vT LDS row stride in shorts (144 B = 16*9, odd multiple of 16B)
#define QSTR 296    // qp/ctx LDS row stride in shorts (592 B = 16*37)

typedef _Float16 half8 __attribute__((ext_vector_type(8)));
typedef float floatx4 __attribute__((ext_vector_type(4)));
typedef short short8 __attribute__((ext_vector_type(8)));
typedef short short4s __attribute__((ext_vector_type(4)));

__device__ __forceinline__ short f2h_bits(float f) {
    union { _Float16 h; short s; } u; u.h = (_Float16)f; return u.s;
}
__device__ __forceinline__ short f2bf_bits(float f) {
    unsigned u = __float_as_uint(f);
    return (short)((u + 0x7FFFu + ((u >> 16) & 1u)) >> 16);
}
__device__ __forceinline__ unsigned encf(float f) {
    unsigned u = __float_as_uint(f);
    return (u & 0x80000000u) ? ~u : (u | 0x80000000u);
}
__device__ __forceinline__ float decf(unsigned u) {
    u = (u & 0x80000000u) ? (u & 0x7FFFFFFFu) : ~u;
    return __uint_as_float(u);
}

// stage proj into LDS as f16(DNORM * proj), rows [272][PSTR]
__device__ __forceinline__ void stage_proj(short* projL, const float* __restrict__ proj, int tid) {
    for (int idx = tid; idx < 544; idx += 512) {
        const int f = idx >> 1, hf = idx & 1;
        const float* src = proj + f * 64 + hf * 32;
        short* dst = &projL[f * PSTR + hf * 32];
        #pragma unroll
        for (int j2 = 0; j2 < 8; ++j2) {
            float4 v4 = *(const float4*)(src + j2 * 4);
            short4s sv;
            sv[0] = f2h_bits(v4.x * DNORM);
            sv[1] = f2h_bits(v4.y * DNORM);
            sv[2] = f2h_bits(v4.z * DNORM);
            sv[3] = f2h_bits(v4.w * DNORM);
            *(short4s*)(dst + j2 * 4) = sv;
        }
    }
}

__global__ __launch_bounds__(512, 1)
void k_pass(const float* __restrict__ kin, const float* __restrict__ vin,
            const float* __restrict__ proj, float* __restrict__ A0p,
            float* __restrict__ S0p, float* __restrict__ Vsp,
            unsigned int* __restrict__ gmax)
{
    __shared__ __align__(16) short projL[MPAD * PSTR];
    __shared__ __align__(16) short epT[MPAD * PSTR];   // ep[m][n] bf16, n=0..63
    __shared__ __align__(16) short vT[64 * PSTR];      // v[n][e] -> vT[e][n] bf16
    __shared__ float red8[8];

    const int tid = threadIdx.x;
    const int bh = blockIdx.x >> 3, ch = blockIdx.x & 7;
    const int c = tid & 15, g = (tid >> 4) & 3, w = tid >> 6;
    const int lane = tid & 63;
    const int a = w & 3, h = w >> 2;       // GEMM1: r-tile, f-half
    const int e4 = w & 3, h2 = w >> 2;     // GEMM2: e-tile, m-half
    const int tb1 = 8 * h, tb2 = 8 * h2;   // tile bases (tile 8 duplicated, benign)

    stage_proj(projL, proj, tid);

    const float* kb = kin + ((size_t)bh * NTOK + (size_t)ch * CHROWS) * DIM;
    const float* vb = vin + ((size_t)bh * NTOK + (size_t)ch * CHROWS) * DIM;

    floatx4 acc9[9];
    float s0acc[9];
    #pragma unroll
    for (int i = 0; i < 9; ++i) {
        acc9[i][0] = 0.f; acc9[i][1] = 0.f; acc9[i][2] = 0.f; acc9[i][3] = 0.f;
        s0acc[i] = 0.f;
    }
    float vsacc = 0.f;
    float dmax = -3.0e38f;

    __syncthreads();   // proj ready

    for (int sub = 0; sub < 8; ++sub) {
        const int n0 = sub * 64;
        // ---- stage vT: wave w covers n-rows 8w..8w+7, lane = e
        {
            const float* vs = vb + (size_t)(n0 + 8 * w) * DIM + lane;
            short8 pk;
            #pragma unroll
            for (int i = 0; i < 8; ++i) {
                float x = vs[(size_t)i * DIM];
                vsacc += x;
                pk[i] = f2bf_bits(x);
            }
            *(short8*)&vT[lane * PSTR + 8 * w] = pk;
        }
        // ---- load k A-frags (rows 16a + c), f16; diag from f32
        half8 af0, af1;
        float dsum = 0.f;
        {
            const float* ks = kb + (size_t)(n0 + 16 * a + c) * DIM;
            #pragma unroll
            for (int ksi = 0; ksi < 2; ++ksi) {
                const float* p4 = ks + ksi * 32 + 8 * g;
                float4 x0 = *(const float4*)p4;
                float4 x1 = *(const float4*)(p4 + 4);
                dsum += x0.x*x0.x + x0.y*x0.y + x0.z*x0.z + x0.w*x0.w
                      + x1.x*x1.x + x1.y*x1.y + x1.z*x1.z + x1.w*x1.w;
                half8& af = ksi ? af1 : af0;
                af[0]=(_Float16)x0.x; af[1]=(_Float16)x0.y; af[2]=(_Float16)x0.z; af[3]=(_Float16)x0.w;
                af[4]=(_Float16)x1.x; af[5]=(_Float16)x1.y; af[6]=(_Float16)x1.z; af[7]=(_Float16)x1.w;
            }
        }
        float t1 = dsum + __shfl_xor(dsum, 16);
        float diagc = (t1 + __shfl_xor(t1, 32)) * DIAGC;   // diag of row c
        float dgr[4];
        #pragma unroll
        for (int r2 = 0; r2 < 4; ++r2) dgr[r2] = __shfl(diagc, 4 * g + r2);

        // ---- GEMM1: dd = k @ projT ; epilogue: ep = exp(dd - diag) -> epT
        #pragma unroll
        for (int i = 0; i < 9; ++i) {
            const int t = tb1 + i;
            const short* bp = &projL[(16 * t + c) * PSTR + 8 * g];
            half8 b0 = *(const half8*)bp;
            half8 b1 = *(const half8*)(bp + 32);
            floatx4 d = {0.f, 0.f, 0.f, 0.f};
            d = __builtin_amdgcn_mfma_f32_16x16x32_f16(af0, b0, d, 0, 0, 0);
            d = __builtin_amdgcn_mfma_f32_16x16x32_f16(af1, b1, d, 0, 0, 0);
            const bool fval = (t < 16) || (c < 10);   // f = 16t + c < 266
            short4s pk;
            float s0t = 0.f;
            #pragma unroll
            for (int r2 = 0; r2 < 4; ++r2) {
                float ddv = d[r2];
                if (fval) dmax = fmaxf(dmax, ddv);
                float ev = __expf(ddv - dgr[r2]);
                s0t += ev;
                pk[r2] = f2bf_bits(ev);
            }
            if (h == 0 || i > 0) s0acc[i] += s0t;     // avoid double-count of tile 8
            *(short4s*)&epT[(16 * t + c) * PSTR + 16 * a + 4 * g] = pk;
        }
        __syncthreads();   // epT + vT complete

        // ---- GEMM2: context += epT @ v  (contract n)
        {
            const short* vp = &vT[(16 * e4 + c) * PSTR + 8 * g];
            short8 vb0 = *(const short8*)vp;
            short8 vb1 = *(const short8*)(vp + 32);
            #pragma unroll
            for (int i = 0; i < 9; ++i) {
                const int t = tb2 + i;
                const short* ap = &epT[(16 * t + c) * PSTR + 8 * g];
                short8 a0 = *(const short8*)ap;
                short8 a1 = *(const short8*)(ap + 32);
                acc9[i] = __builtin_amdgcn_mfma_f32_16x16x32_bf16(a0, vb0, acc9[i], 0, 0, 0);
                acc9[i] = __builtin_amdgcn_mfma_f32_16x16x32_bf16(a1, vb1, acc9[i], 0, 0, 0);
            }
        }
        __syncthreads();   // done reading; next sub may overwrite
    }

    // ---- write A0 partials [m][e]
    {
        float* dst = A0p + (size_t)(bh * NCH + ch) * (MPAD * 64);
        #pragma unroll
        for (int i = 0; i < 9; ++i) {
            const int t = tb2 + i;
            #pragma unroll
            for (int r2 = 0; r2 < 4; ++r2)
                dst[(size_t)(16 * t + 4 * g + r2) * 64 + 16 * e4 + c] = acc9[i][r2];
        }
    }
    // ---- S0 atomics (reduce over g first)
    #pragma unroll
    for (int i = 0; i < 9; ++i) {
        float s = s0acc[i];
        s += __shfl_xor(s, 16); s += __shfl_xor(s, 32);
        if (g == 0) atomicAdd(&S0p[bh * MPAD + 16 * (tb1 + i) + c], s);
    }
    atomicAdd(&Vsp[bh * 64 + lane], vsacc);
    // ---- dmax
    #pragma unroll
    for (int s = 1; s <= 32; s <<= 1) dmax = fmaxf(dmax, __shfl_xor(dmax, s));
    if (lane == 0) red8[w] = dmax;
    __syncthreads();
    if (tid == 0) {
        float m = red8[0];
        #pragma unroll
        for (int i = 1; i < 8; ++i) m = fmaxf(m, red8[i]);
        atomicMax(gmax + bh, encf(m));
    }
}

// ctxT_ws[bh][e'][m] f16, e'=0..63 context cols, e'=64 k_cumsum; m padded to 288 with zeros
__global__ __launch_bounds__(512, 1)
void reduce_ctx(const float* __restrict__ A0p, const float* __restrict__ S0p,
                const float* __restrict__ Vsp, const unsigned int* __restrict__ gmax,
                short* __restrict__ ctxw)
{
    __shared__ __align__(16) short L[65 * 288];
    const int bh = blockIdx.x, tid = threadIdx.x;
    const float emx = __expf(-decf(gmax[bh]));
    const int e = tid & 63, mi = tid >> 6;
    const float vsr = Vsp[bh * 64 + e] * KEPS;
    const float* base = A0p + (size_t)bh * NCH * MPAD * 64;
    for (int m = mi; m < 288; m += 8) {
        float val = 0.f;
        if (m < MF) {
            float s = 0.f;
            #pragma unroll
            for (int c2 = 0; c2 < NCH; ++c2)
                s += base[(size_t)c2 * MPAD * 64 + (size_t)m * 64 + e];
            val = RATIO * (emx * s + vsr);
        }
        L[e * 288 + m] = f2h_bits(val);
    }
    for (int m = tid; m < 288; m += 512) {
        float val = 0.f;
        if (m < MF) val = RATIO * (emx * S0p[bh * MPAD + m] + KEPS * 4096.0f);
        L[64 * 288 + m] = f2h_bits(val);
    }
    __syncthreads();
    short* dst = ctxw + (size_t)bh * (65 * 288);
    for (int idx = tid; idx < 65 * 36; idx += 512)
        *(short8*)(dst + idx * 8) = *(const short8*)&L[idx * 8];
}

__global__ __launch_bounds__(512, 1)
void q_pass(const float* __restrict__ qin, const float* __restrict__ proj,
            const short* __restrict__ ctxw, float* __restrict__ outp)
{
    __shared__ __align__(16) short projL[MPAD * PSTR];
    __shared__ __align__(16) short ctxL[65 * QSTR];    // ctxT[e'][m] f16
    __shared__ __align__(16) short qpL[128 * QSTR];    // qp[r][m] f16

    const int tid = threadIdx.x;
    const int bh = blockIdx.x >> 5, rt = blockIdx.x & 31;
    const int c = tid & 15, g = (tid >> 4) & 3, w = tid >> 6;

    stage_proj(projL, proj, tid);
    {
        const short* src = ctxw + (size_t)bh * (65 * 288);
        for (int idx = tid; idx < 65 * 36; idx += 512) {
            const int r = idx / 36, s = idx - r * 36;
            *(short8*)&ctxL[r * QSTR + s * 8] = *(const short8*)(src + r * 288 + s * 8);
        }
    }
    // ---- load q B-frags (row R0 = rt*128 + 16w + c), diag
    half8 bf0, bf1;
    float dsum = 0.f;
    {
        const float* qs = qin + ((size_t)bh * NTOK + rt * 128 + 16 * w + c) * DIM;
        #pragma unroll
        for (int ksi = 0; ksi < 2; ++ksi) {
            const float* p4 = qs + ksi * 32 + 8 * g;
            float4 x0 = *(const float4*)p4;
            float4 x1 = *(const float4*)(p4 + 4);
            dsum += x0.x*x0.x + x0.y*x0.y + x0.z*x0.z + x0.w*x0.w
                  + x1.x*x1.x + x1.y*x1.y + x1.z*x1.z + x1.w*x1.w;
            half8& bf = ksi ? bf1 : bf0;
            bf[0]=(_Float16)x0.x; bf[1]=(_Float16)x0.y; bf[2]=(_Float16)x0.z; bf[3]=(_Float16)x0.w;
            bf[4]=(_Float16)x1.x; bf[5]=(_Float16)x1.y; bf[6]=(_Float16)x1.z; bf[7]=(_Float16)x1.w;
        }
    }
    float t1 = dsum + __shfl_xor(dsum, 16);
    const float diagc = (t1 + __shfl_xor(t1, 32)) * DIAGC;   // diag of own row c

    __syncthreads();   // proj + ctx ready

    // ---- GEMM1: dd^T = proj @ q^T : D col = r (=c), row = f-within-tile (4g+reg)
    floatx4 dd[17];
    #pragma unroll
    for (int t = 0; t < 17; ++t) {
        const short* ap = &projL[(16 * t + c) * PSTR + 8 * g];
        half8 a0 = *(const half8*)ap;
        half8 a1 = *(const half8*)(ap + 32);
        floatx4 d = {0.f, 0.f, 0.f, 0.f};
        d = __builtin_amdgcn_mfma_f32_16x16x32_f16(a0, bf0, d, 0, 0, 0);
        d = __builtin_amdgcn_mfma_f32_16x16x32_f16(a1, bf1, d, 0, 0, 0);
        dd[t] = d;
    }
    // ---- per-row max over valid f
    float mx = -3.0e38f;
    #pragma unroll
    for (int t = 0; t < 17; ++t) {
        #pragma unroll
        for (int r2 = 0; r2 < 4; ++r2) {
            const bool fval = (t < 16) || (4 * g + r2 < 10);
            if (fval) mx = fmaxf(mx, dd[t][r2]);
        }
    }
    mx = fmaxf(mx, __shfl_xor(mx, 16));
    mx = fmaxf(mx, __shfl_xor(mx, 32));
    // ---- qp = exp(dd - diag - mx) + eps -> qpL (4 consecutive m per lane)
    const int qrow = (16 * w + c) * QSTR;
    #pragma unroll
    for (int t = 0; t < 17; ++t) {
        short4s pk;
        #pragma unroll
        for (int r2 = 0; r2 < 4; ++r2)
            pk[r2] = f2h_bits(__expf(dd[t][r2] - diagc - mx) + KEPS);
        *(short4s*)&qpL[qrow + 16 * t + 4 * g] = pk;
    }
    {   // zero-pad m = 272..287
        short4s z; z[0]=0; z[1]=0; z[2]=0; z[3]=0;
        *(short4s*)&qpL[qrow + 272 + 4 * g] = z;
    }
    __syncthreads();

    // ---- GEMM2: out[r][e'] = qp @ ctx (contract m, 9 K-steps of 32)
    floatx4 acc5[5];
    #pragma unroll
    for (int i = 0; i < 5; ++i) { acc5[i][0]=0.f; acc5[i][1]=0.f; acc5[i][2]=0.f; acc5[i][3]=0.f; }
    half8 hz; 
    #pragma unroll
    for (int j = 0; j < 8; ++j) hz[j] = (_Float16)0.f;
    #pragma unroll
    for (int ms = 0; ms < 9; ++ms) {
        half8 aq = *(const half8*)&qpL[qrow + 32 * ms + 8 * g];
        #pragma unroll
        for (int e4 = 0; e4 < 5; ++e4) {
            const int rr = (e4 < 4) ? (16 * e4 + c) : 64;
            half8 bcx = *(const half8*)&ctxL[rr * QSTR + 32 * ms + 8 * g];
            if (e4 == 4 && c != 0) bcx = hz;
            acc5[e4] = __builtin_amdgcn_mfma_f32_16x16x32_f16(aq, bcx, acc5[e4], 0, 0, 0);
        }
    }
    // ---- den broadcast, normalize, store
    float* ob = outp + ((size_t)bh * NTOK + rt * 128 + 16 * w) * DIM;
    #pragma unroll
    for (int r2 = 0; r2 < 4; ++r2) {
        float den = __shfl(acc5[4][r2], (tid & 48));
        if (den == 0.f) den = 1e-5f;
        const float inv = 1.0f / den;
        const int row = 4 * g + r2;
        #pragma unroll
        for (int t = 0; t < 4; ++t)
            ob[(size_t)row * DIM + 16 * t + c] = acc5[t][r2] * inv;
    }
}

extern "C" void kernel_launch(void* const* d_in, const int* in_sizes, int n_in,
                              void* d_out, int out_size, void* d_ws, size_t ws_size,
                              hipStream_t stream)
{
    const float* q    = (const float*)d_in[0];
    const float* k    = (const float*)d_in[1];
    const float* v    = (const float*)d_in[2];
    const float* proj = (const float*)d_in[3];
    float* out = (float*)d_out;
    float* ws  = (float*)d_ws;

    const size_t offS = (size_t)BH * NCH * MPAD * 64;   // A0p partials: 8,912,896 floats
    const size_t offV = offS + (size_t)BH * MPAD;       // S0p (atomic f32)
    const size_t offG = offV + (size_t)BH * 64;         // Vsp (atomic f32)
    const size_t offC = offG + 64;                      // gmax (encoded uint)
    // ctxT f16 at offC: 64 * 65 * 288 shorts = 599,040 float-slots; total ~38.1 MB

    float* A0p = ws;
    float* S0p = ws + offS;
    float* Vsp = ws + offV;
    unsigned int* gmax = (unsigned int*)(ws + offG);
    short* ctxw = (short*)(ws + offC);

    // zero S0p + Vsp + gmax (contiguous)
    hipMemsetAsync(S0p, 0, ((size_t)BH * MPAD + (size_t)BH * 64 + 64) * sizeof(float), stream);
    hipLaunchKernelGGL(k_pass, dim3(BH * NCH), dim3(512), 0, stream,
                       k, v, proj, A0p, S0p, Vsp, gmax);
    hipLaunchKernelGGL(reduce_ctx, dim3(BH), dim3(512), 0, stream,
                       A0p, S0p, Vsp, gmax, ctxw);
    hipLaunchKernelGGL(q_pass, dim3(BH * 32), dim3(512), 0, stream,
                       q, proj, ctxw, out);
}

// Round 3
// 165.350 us; speedup vs baseline: 6.2402x; 1.1129x over previous
//
#include <hip/hip_runtime.h>
#include <math.h>

// Performer FAVOR+ fast attention — round 3.
// B=4 H=16 N=4096 D=64 M=266.
// k_pass: proj in regs, double-buffered epT/vT, reg-prefetch, 1 barrier/sub.
// q_pass: GEMM2 via mfma 16x16x16 with qp held in registers (no qpL), 2 blocks/CU.

#define BH 64
#define NTOK 4096
#define DIM 64
#define MF 266
#define MPAD 272
#define NCH 8
#define CHROWS 512
#define RATIO 0.06131393394849658f   // 266^-0.5
#define DNORM 0.35355339059327373f   // 64^-0.25
#define DIAGC 0.0625f                // 0.5 * 64^-0.5
#define KEPS 1e-4f

#define PSTR 72     // epT/vT/projL LDS row stride in shorts (144 B)
#define QSTR 296    // ctx LDS row stride in shorts (592 B)

typedef _Float16 half8 __attribute__((ext_vector_type(8)));
typedef _Float16 half4 __attribute__((ext_vector_type(4)));
typedef float floatx4 __attribute__((ext_vector_type(4)));
typedef short short8 __attribute__((ext_vector_type(8)));
typedef short short4s __attribute__((ext_vector_type(4)));

__device__ __forceinline__ short f2h_bits(float f) {
    union { _Float16 h; short s; } u; u.h = (_Float16)f; return u.s;
}
__device__ __forceinline__ float h2f(short s) {
    union { short s; _Float16 h; } u; u.s = s; return (float)u.h;
}
__device__ __forceinline__ short f2bf_bits(float f) {
    unsigned u = __float_as_uint(f);
    return (short)((u + 0x7FFFu + ((u >> 16) & 1u)) >> 16);
}
__device__ __forceinline__ unsigned encf(float f) {
    unsigned u = __float_as_uint(f);
    return (u & 0x80000000u) ? ~u : (u | 0x80000000u);
}
__device__ __forceinline__ float decf(unsigned u) {
    u = (u & 0x80000000u) ? (u & 0x7FFFFFFFu) : ~u;
    return __uint_as_float(u);
}

// stage proj into LDS as f16(DNORM * proj), rows [272][PSTR]; rows >= 266 zeroed
__device__ __forceinline__ void stage_proj(short* projL, const float* __restrict__ proj, int tid) {
    for (int idx = tid; idx < 544; idx += 512) {
        const int f = idx >> 1, hf = idx & 1;
        short* dst = &projL[f * PSTR + hf * 32];
        if (f < MF) {
            const float* src = proj + f * 64 + hf * 32;
            #pragma unroll
            for (int j2 = 0; j2 < 8; ++j2) {
                float4 v4 = *(const float4*)(src + j2 * 4);
                short4s sv;
                sv[0] = f2h_bits(v4.x * DNORM);
                sv[1] = f2h_bits(v4.y * DNORM);
                sv[2] = f2h_bits(v4.z * DNORM);
                sv[3] = f2h_bits(v4.w * DNORM);
                *(short4s*)(dst + j2 * 4) = sv;
            }
        } else {
            short4s z; z[0] = 0; z[1] = 0; z[2] = 0; z[3] = 0;
            #pragma unroll
            for (int j2 = 0; j2 < 8; ++j2) *(short4s*)(dst + j2 * 4) = z;
        }
    }
}

__global__ __launch_bounds__(512, 2)
void k_pass(const float* __restrict__ kin, const float* __restrict__ vin,
            const float* __restrict__ proj, float* __restrict__ A0p,
            float* __restrict__ S0p, float* __restrict__ Vsp,
            unsigned int* __restrict__ gmax)
{
    __shared__ __align__(16) short epT[2][MPAD * PSTR];   // ep[m][n] bf16 (dbuf)
    __shared__ __align__(16) short vT[2][64 * PSTR];      // vT[e][n] bf16 (dbuf)
    __shared__ float red8[8];

    const int tid = threadIdx.x;
    const int bh = blockIdx.x >> 3, ch = blockIdx.x & 7;
    const int c = tid & 15, g = (tid >> 4) & 3, w = tid >> 6;
    const int lane = tid & 63;
    const int a = w & 3, h = w >> 2;   // a: n-16-chunk (G1) / e-tile (G2); h: feature half
    const int tb = 8 * h;              // tile base (tile 8 duplicated across halves, benign)

    // ---- proj B-frags in registers: B[k=8g+j][col=c] = DNORM*proj[16t+c][d]
    half8 pb0[9], pb1[9];
    #pragma unroll
    for (int i = 0; i < 9; ++i) {
        const int f = 16 * (tb + i) + c;
        if (f < MF) {
            const float* ps = proj + (size_t)f * 64 + 8 * g;
            float4 x0 = *(const float4*)ps;
            float4 x1 = *(const float4*)(ps + 4);
            float4 x2 = *(const float4*)(ps + 32);
            float4 x3 = *(const float4*)(ps + 36);
            half8 b0, b1;
            b0[0]=(_Float16)(DNORM*x0.x); b0[1]=(_Float16)(DNORM*x0.y);
            b0[2]=(_Float16)(DNORM*x0.z); b0[3]=(_Float16)(DNORM*x0.w);
            b0[4]=(_Float16)(DNORM*x1.x); b0[5]=(_Float16)(DNORM*x1.y);
            b0[6]=(_Float16)(DNORM*x1.z); b0[7]=(_Float16)(DNORM*x1.w);
            b1[0]=(_Float16)(DNORM*x2.x); b1[1]=(_Float16)(DNORM*x2.y);
            b1[2]=(_Float16)(DNORM*x2.z); b1[3]=(_Float16)(DNORM*x2.w);
            b1[4]=(_Float16)(DNORM*x3.x); b1[5]=(_Float16)(DNORM*x3.y);
            b1[6]=(_Float16)(DNORM*x3.z); b1[7]=(_Float16)(DNORM*x3.w);
            pb0[i] = b0; pb1[i] = b1;
        } else {
            half8 z;
            #pragma unroll
            for (int j = 0; j < 8; ++j) z[j] = (_Float16)0.f;
            pb0[i] = z; pb1[i] = z;
        }
    }

    const float* kb = kin + ((size_t)bh * NTOK + (size_t)ch * CHROWS) * DIM;
    const float* vb = vin + ((size_t)bh * NTOK + (size_t)ch * CHROWS) * DIM;

    floatx4 acc9[9];
    float s0acc[9];
    #pragma unroll
    for (int i = 0; i < 9; ++i) {
        acc9[i][0] = 0.f; acc9[i][1] = 0.f; acc9[i][2] = 0.f; acc9[i][3] = 0.f;
        s0acc[i] = 0.f;
    }
    float vsacc = 0.f;
    float dmax = -3.0e38f;

    float4 kx0, kx1, kx2, kx3;
    float vx[8];

    auto prefetch = [&](int s) {
        const int n0 = s * 64;
        const float* ks = kb + (size_t)(n0 + 16 * a + c) * DIM + 8 * g;
        kx0 = *(const float4*)ks;
        kx1 = *(const float4*)(ks + 4);
        kx2 = *(const float4*)(ks + 32);
        kx3 = *(const float4*)(ks + 36);
        const float* vs = vb + (size_t)(n0 + 8 * w) * DIM + lane;
        #pragma unroll
        for (int i = 0; i < 8; ++i) vx[i] = vs[(size_t)i * DIM];
    };

    auto g1 = [&](int buf) {
        // vT write (wave w covers n-rows 8w..8w+7, lane = e)
        short8 pk;
        #pragma unroll
        for (int i = 0; i < 8; ++i) { vsacc += vx[i]; pk[i] = f2bf_bits(vx[i]); }
        *(short8*)&vT[buf][lane * PSTR + 8 * w] = pk;
        // A-frags + diag
        half8 af0, af1;
        float dsum = kx0.x*kx0.x + kx0.y*kx0.y + kx0.z*kx0.z + kx0.w*kx0.w
                   + kx1.x*kx1.x + kx1.y*kx1.y + kx1.z*kx1.z + kx1.w*kx1.w
                   + kx2.x*kx2.x + kx2.y*kx2.y + kx2.z*kx2.z + kx2.w*kx2.w
                   + kx3.x*kx3.x + kx3.y*kx3.y + kx3.z*kx3.z + kx3.w*kx3.w;
        af0[0]=(_Float16)kx0.x; af0[1]=(_Float16)kx0.y; af0[2]=(_Float16)kx0.z; af0[3]=(_Float16)kx0.w;
        af0[4]=(_Float16)kx1.x; af0[5]=(_Float16)kx1.y; af0[6]=(_Float16)kx1.z; af0[7]=(_Float16)kx1.w;
        af1[0]=(_Float16)kx2.x; af1[1]=(_Float16)kx2.y; af1[2]=(_Float16)kx2.z; af1[3]=(_Float16)kx2.w;
        af1[4]=(_Float16)kx3.x; af1[5]=(_Float16)kx3.y; af1[6]=(_Float16)kx3.z; af1[7]=(_Float16)kx3.w;
        float t1 = dsum + __shfl_xor(dsum, 16);
        float diagc = (t1 + __shfl_xor(t1, 32)) * DIAGC;
        float dgr[4];
        #pragma unroll
        for (int r2 = 0; r2 < 4; ++r2) dgr[r2] = __shfl(diagc, 4 * g + r2);
        #pragma unroll
        for (int i = 0; i < 9; ++i) {
            const int t = tb + i;
            floatx4 d = {0.f, 0.f, 0.f, 0.f};
            d = __builtin_amdgcn_mfma_f32_16x16x32_f16(af0, pb0[i], d, 0, 0, 0);
            d = __builtin_amdgcn_mfma_f32_16x16x32_f16(af1, pb1[i], d, 0, 0, 0);
            const bool fval = (t < 16) || (c < 10);   // f = 16t + c < 266
            short4s pkk; float s0t = 0.f;
            #pragma unroll
            for (int r2 = 0; r2 < 4; ++r2) {
                float ddv = d[r2];
                if (fval) dmax = fmaxf(dmax, ddv);
                float ev = __expf(ddv - dgr[r2]);
                s0t += ev;
                pkk[r2] = f2bf_bits(ev);
            }
            if (h == 0 || i > 0) s0acc[i] += s0t;
            *(short4s*)&epT[buf][(16 * t + c) * PSTR + 16 * a + 4 * g] = pkk;
        }
    };

    auto g2 = [&](int buf) {
        const short* vp = &vT[buf][(16 * a + c) * PSTR + 8 * g];
        short8 vb0 = *(const short8*)vp;
        short8 vb1 = *(const short8*)(vp + 32);
        #pragma unroll
        for (int i = 0; i < 9; ++i) {
            const short* ap = &epT[buf][(16 * (tb + i) + c) * PSTR + 8 * g];
            short8 a0 = *(const short8*)ap;
            short8 a1 = *(const short8*)(ap + 32);
            acc9[i] = __builtin_amdgcn_mfma_f32_16x16x32_bf16(a0, vb0, acc9[i], 0, 0, 0);
            acc9[i] = __builtin_amdgcn_mfma_f32_16x16x32_bf16(a1, vb1, acc9[i], 0, 0, 0);
        }
    };

    prefetch(0);
    g1(0);
    __syncthreads();
    for (int s = 0; s < 8; ++s) {
        if (s < 7) prefetch(s + 1);
        g2(s & 1);
        if (s < 7) {
            g1((s + 1) & 1);
            __syncthreads();
        }
    }

    // ---- write A0 partials [m][e]
    {
        float* dst = A0p + (size_t)(bh * NCH + ch) * (MPAD * 64);
        #pragma unroll
        for (int i = 0; i < 9; ++i) {
            const int t = tb + i;
            #pragma unroll
            for (int r2 = 0; r2 < 4; ++r2)
                dst[(size_t)(16 * t + 4 * g + r2) * 64 + 16 * a + c] = acc9[i][r2];
        }
    }
    #pragma unroll
    for (int i = 0; i < 9; ++i) {
        float s = s0acc[i];
        s += __shfl_xor(s, 16); s += __shfl_xor(s, 32);
        if (g == 0) atomicAdd(&S0p[bh * MPAD + 16 * (tb + i) + c], s);
    }
    atomicAdd(&Vsp[bh * 64 + lane], vsacc);
    #pragma unroll
    for (int s = 1; s <= 32; s <<= 1) dmax = fmaxf(dmax, __shfl_xor(dmax, s));
    if (lane == 0) red8[w] = dmax;
    __syncthreads();
    if (tid == 0) {
        float m = red8[0];
        #pragma unroll
        for (int i = 1; i < 8; ++i) m = fmaxf(m, red8[i]);
        atomicMax(gmax + bh, encf(m));
    }
}

// ctxT_ws[bh][e'][m] f16, e'=0..63 context cols, e'=64 k_cumsum; m padded to 288 with zeros
__global__ __launch_bounds__(512, 1)
void reduce_ctx(const float* __restrict__ A0p, const float* __restrict__ S0p,
                const float* __restrict__ Vsp, const unsigned int* __restrict__ gmax,
                short* __restrict__ ctxw)
{
    __shared__ __align__(16) short L[65 * 288];
    const int bh = blockIdx.x, tid = threadIdx.x;
    const float emx = __expf(-decf(gmax[bh]));
    const int e = tid & 63, mi = tid >> 6;
    const float vsr = Vsp[bh * 64 + e] * KEPS;
    const float* base = A0p + (size_t)bh * NCH * MPAD * 64;
    for (int m = mi; m < 288; m += 8) {
        float val = 0.f;
        if (m < MF) {
            float s = 0.f;
            #pragma unroll
            for (int c2 = 0; c2 < NCH; ++c2)
                s += base[(size_t)c2 * MPAD * 64 + (size_t)m * 64 + e];
            val = RATIO * (emx * s + vsr);
        }
        L[e * 288 + m] = f2h_bits(val);
    }
    for (int m = tid; m < 288; m += 512) {
        float val = 0.f;
        if (m < MF) val = RATIO * (emx * S0p[bh * MPAD + m] + KEPS * 4096.0f);
        L[64 * 288 + m] = f2h_bits(val);
    }
    __syncthreads();
    short* dst = ctxw + (size_t)bh * (65 * 288);
    for (int idx = tid; idx < 65 * 36; idx += 512)
        *(short8*)(dst + idx * 8) = *(const short8*)&L[idx * 8];
}

__global__ __launch_bounds__(512, 2)
void q_pass(const float* __restrict__ qin, const float* __restrict__ proj,
            const short* __restrict__ ctxw, float* __restrict__ outp)
{
    __shared__ __align__(16) short projL[MPAD * PSTR];
    __shared__ __align__(16) short ctxL[65 * QSTR];    // ctxT[e'][m] f16

    const int tid = threadIdx.x;
    const int bh = blockIdx.x >> 5, rt = blockIdx.x & 31;
    const int c = tid & 15, g = (tid >> 4) & 3, w = tid >> 6;

    stage_proj(projL, proj, tid);
    {
        const short* src = ctxw + (size_t)bh * (65 * 288);
        for (int idx = tid; idx < 65 * 36; idx += 512) {
            const int r = idx / 36, s = idx - r * 36;
            *(short8*)&ctxL[r * QSTR + s * 8] = *(const short8*)(src + r * 288 + s * 8);
        }
    }
    // ---- load q B-frags (row R0 = rt*128 + 16w + c), diag
    half8 bf0, bf1;
    float dsum = 0.f;
    {
        const float* qs = qin + ((size_t)bh * NTOK + rt * 128 + 16 * w + c) * DIM;
        #pragma unroll
        for (int ksi = 0; ksi < 2; ++ksi) {
            const float* p4 = qs + ksi * 32 + 8 * g;
            float4 x0 = *(const float4*)p4;
            float4 x1 = *(const float4*)(p4 + 4);
            dsum += x0.x*x0.x + x0.y*x0.y + x0.z*x0.z + x0.w*x0.w
                  + x1.x*x1.x + x1.y*x1.y + x1.z*x1.z + x1.w*x1.w;
            half8& bf = ksi ? bf1 : bf0;
            bf[0]=(_Float16)x0.x; bf[1]=(_Float16)x0.y; bf[2]=(_Float16)x0.z; bf[3]=(_Float16)x0.w;
            bf[4]=(_Float16)x1.x; bf[5]=(_Float16)x1.y; bf[6]=(_Float16)x1.z; bf[7]=(_Float16)x1.w;
        }
    }
    float t1 = dsum + __shfl_xor(dsum, 16);
    const float diagc = (t1 + __shfl_xor(t1, 32)) * DIAGC;   // diag of own row c

    __syncthreads();   // proj + ctx ready

    // ---- GEMM1: dd^T = proj @ q^T : lane (c,g) holds dd[f=16t+4g+r2][row=c]
    floatx4 dd[17];
    #pragma unroll
    for (int t = 0; t < 17; ++t) {
        const short* ap = &projL[(16 * t + c) * PSTR + 8 * g];
        half8 a0 = *(const half8*)ap;
        half8 a1 = *(const half8*)(ap + 32);
        floatx4 d = {0.f, 0.f, 0.f, 0.f};
        d = __builtin_amdgcn_mfma_f32_16x16x32_f16(a0, bf0, d, 0, 0, 0);
        d = __builtin_amdgcn_mfma_f32_16x16x32_f16(a1, bf1, d, 0, 0, 0);
        dd[t] = d;
    }
    // ---- per-row max over valid f
    float mx = -3.0e38f;
    #pragma unroll
    for (int t = 0; t < 17; ++t) {
        #pragma unroll
        for (int r2 = 0; r2 < 4; ++r2) {
            const bool fval = (t < 16) || (4 * g + r2 < 10);
            if (fval) mx = fmaxf(mx, dd[t][r2]);
        }
    }
    mx = fmaxf(mx, __shfl_xor(mx, 16));
    mx = fmaxf(mx, __shfl_xor(mx, 32));

    // ---- qp in registers as 16x16x16 B-frags; denominator via VALU dot
    half4 bq[17];
    float denp = 0.f;
    #pragma unroll
    for (int t = 0; t < 17; ++t) {
        half4 b;
        #pragma unroll
        for (int r2 = 0; r2 < 4; ++r2) {
            float val = __expf(dd[t][r2] - diagc - mx) + KEPS;
            b[r2] = (_Float16)val;
            denp += val * h2f(ctxL[64 * QSTR + 16 * t + 4 * g + r2]);
        }
        bq[t] = b;
    }
    denp += __shfl_xor(denp, 16);
    denp += __shfl_xor(denp, 32);

    // ---- GEMM2: out^T[e'][r] = ctxT @ qp^T  (contract m, 17 K-steps of 16)
    floatx4 acc[4];
    #pragma unroll
    for (int i = 0; i < 4; ++i) { acc[i][0]=0.f; acc[i][1]=0.f; acc[i][2]=0.f; acc[i][3]=0.f; }
    #pragma unroll
    for (int e4 = 0; e4 < 4; ++e4) {
        #pragma unroll
        for (int t = 0; t < 17; ++t) {
            half4 a4 = *(const half4*)&ctxL[(16 * e4 + c) * QSTR + 16 * t + 4 * g];
            acc[e4] = __builtin_amdgcn_mfma_f32_16x16x16f16(a4, bq[t], acc[e4], 0, 0, 0);
        }
    }
    // ---- normalize + store: lane (c,g) holds out[row c][e' = 16e4+4g+r2]
    float den = (denp == 0.f) ? 1e-5f : denp;
    const float inv = 1.0f / den;
    float* ob = outp + ((size_t)bh * NTOK + rt * 128 + 16 * w + c) * DIM;
    #pragma unroll
    for (int e4 = 0; e4 < 4; ++e4) {
        float4 o = make_float4(acc[e4][0] * inv, acc[e4][1] * inv,
                               acc[e4][2] * inv, acc[e4][3] * inv);
        *(float4*)(ob + 16 * e4 + 4 * g) = o;
    }
}

extern "C" void kernel_launch(void* const* d_in, const int* in_sizes, int n_in,
                              void* d_out, int out_size, void* d_ws, size_t ws_size,
                              hipStream_t stream)
{
    const float* q    = (const float*)d_in[0];
    const float* k    = (const float*)d_in[1];
    const float* v    = (const float*)d_in[2];
    const float* proj = (const float*)d_in[3];
    float* out = (float*)d_out;
    float* ws  = (float*)d_ws;

    const size_t offS = (size_t)BH * NCH * MPAD * 64;   // A0p partials
    const size_t offV = offS + (size_t)BH * MPAD;       // S0p (atomic f32)
    const size_t offG = offV + (size_t)BH * 64;         // Vsp (atomic f32)
    const size_t offC = offG + 64;                      // gmax (encoded uint)

    float* A0p = ws;
    float* S0p = ws + offS;
    float* Vsp = ws + offV;
    unsigned int* gmax = (unsigned int*)(ws + offG);
    short* ctxw = (short*)(ws + offC);

    hipMemsetAsync(S0p, 0, ((size_t)BH * MPAD + (size_t)BH * 64 + 64) * sizeof(float), stream);
    hipLaunchKernelGGL(k_pass, dim3(BH * NCH), dim3(512), 0, stream,
                       k, v, proj, A0p, S0p, Vsp, gmax);
    hipLaunchKernelGGL(reduce_ctx, dim3(BH), dim3(512), 0, stream,
                       A0p, S0p, Vsp, gmax, ctxw);
    hipLaunchKernelGGL(q_pass, dim3(BH * 32), dim3(512), 0, stream,
                       q, proj, ctxw, out);
}

// Round 5
// 144.283 us; speedup vs baseline: 7.1513x; 1.1460x over previous
//
#include <hip/hip_runtime.h>
#include <math.h>

// Performer FAVOR+ fast attention — round 5 (round 4 + compile fix).
// B=4 H=16 N=4096 D=64 M=266.
// k_pass restructured: f-tile-per-wave, ep via wave-private LDS (no barrier),
// k/v f16/bf16 LDS dbuf (1 barrier/sub), VGPR<=128 for 4 waves/SIMD,
// "ones feature" row 271 computes Vs for free. NCH=4.

#define BH 64
#define NTOK 4096
#define DIM 64
#define MF 266
#define MPAD 272
#define NCH 4
#define CHROWS 1024
#define SUBS 16
#define RATIO 0.06131393394849658f   // 266^-0.5
#define DNORM 0.35355339059327373f   // 64^-0.25
#define DIAGC 0.0625f                // 0.5 * 64^-0.5
#define KEPS 1e-4f

#define PSTR 72     // LDS row stride in shorts (144 B)
#define QSTR 296    // q_pass ctx stride in shorts (592 B)

typedef _Float16 half8 __attribute__((ext_vector_type(8)));
typedef _Float16 half4 __attribute__((ext_vector_type(4)));
typedef __fp16 fp16x2 __attribute__((ext_vector_type(2)));   // cvt_pkrtz native type
typedef float floatx4 __attribute__((ext_vector_type(4)));
typedef short short8 __attribute__((ext_vector_type(8)));
typedef short short4s __attribute__((ext_vector_type(4)));

__device__ __forceinline__ short f2h_bits(float f) {
    union { _Float16 h; short s; } u; u.h = (_Float16)f; return u.s;
}
__device__ __forceinline__ float h2f(short s) {
    union { short s; _Float16 h; } u; u.s = s; return (float)u.h;
}
__device__ __forceinline__ unsigned cvt_pk_bf16(float lo, float hi) {
    unsigned r;
    asm("v_cvt_pk_bf16_f32 %0, %1, %2" : "=v"(r) : "v"(lo), "v"(hi));
    return r;
}
__device__ __forceinline__ unsigned encf(float f) {
    unsigned u = __float_as_uint(f);
    return (u & 0x80000000u) ? ~u : (u | 0x80000000u);
}
__device__ __forceinline__ float decf(unsigned u) {
    u = (u & 0x80000000u) ? (u & 0x7FFFFFFFu) : ~u;
    return __uint_as_float(u);
}

// ---------------------------------------------------------------- k_pass ----
__global__ __launch_bounds__(512, 4)
void k_pass(const float* __restrict__ kin, const float* __restrict__ vin,
            const float* __restrict__ proj, float* __restrict__ A0p,
            float* __restrict__ S0p, unsigned int* __restrict__ gmax)
{
    __shared__ __align__(16) short kL[2][64 * PSTR];    // k f16 [n][d]
    __shared__ __align__(16) short vT[2][64 * PSTR];    // v bf16 [e][n]
    __shared__ float diagL[2][64];
    __shared__ __align__(16) short epS[16][16 * PSTR];  // per (wave,it): ep bf16 [f][n]

    const int tid = threadIdx.x;
    const int l = tid & 63, w = tid >> 6;
    const int c = tid & 15, g = (tid >> 4) & 3;
    const int bh = blockIdx.x >> 3;
    const int ch = (blockIdx.x >> 1) & 3;
    const int h  = blockIdx.x & 1;
    const int nT = (h == 1 && w == 0) ? 2 : 1;
    const int t0 = (h == 0) ? w : (8 + w);              // second tile (it=1) is 16

    // ---- proj B-frags in registers (only this wave's tiles)
    half8 pj0[2], pj1[2];
    #pragma unroll
    for (int it = 0; it < 2; ++it) {
        half8 z;
        #pragma unroll
        for (int j = 0; j < 8; ++j) z[j] = (_Float16)0.f;
        pj0[it] = z; pj1[it] = z;
        const int t = it ? 16 : t0;
        const int f = 16 * t + c;
        if (it < nT && f < MF) {
            const float* ps = proj + (size_t)f * 64 + 8 * g;
            float4 x0 = *(const float4*)ps;
            float4 x1 = *(const float4*)(ps + 4);
            float4 x2 = *(const float4*)(ps + 32);
            float4 x3 = *(const float4*)(ps + 36);
            half8 b0, b1;
            b0[0]=(_Float16)(DNORM*x0.x); b0[1]=(_Float16)(DNORM*x0.y);
            b0[2]=(_Float16)(DNORM*x0.z); b0[3]=(_Float16)(DNORM*x0.w);
            b0[4]=(_Float16)(DNORM*x1.x); b0[5]=(_Float16)(DNORM*x1.y);
            b0[6]=(_Float16)(DNORM*x1.z); b0[7]=(_Float16)(DNORM*x1.w);
            b1[0]=(_Float16)(DNORM*x2.x); b1[1]=(_Float16)(DNORM*x2.y);
            b1[2]=(_Float16)(DNORM*x2.z); b1[3]=(_Float16)(DNORM*x2.w);
            b1[4]=(_Float16)(DNORM*x3.x); b1[5]=(_Float16)(DNORM*x3.y);
            b1[6]=(_Float16)(DNORM*x3.z); b1[7]=(_Float16)(DNORM*x3.w);
            pj0[it] = b0; pj1[it] = b1;
        }
    }

    const float* kb = kin + ((size_t)bh * NTOK + (size_t)ch * CHROWS) * DIM;
    const float* vb = vin + ((size_t)bh * NTOK + (size_t)ch * CHROWS) * DIM;

    // staging assignments
    const int srow = 8 * w + (l >> 3);     // k: row, d-segment (l&7)*8
    const int sd0  = (l & 7) * 8;
    const int vrow = l;                    // v: row = lane, e-segment 8w..8w+7
    const int ve0  = 8 * w;

    floatx4 acc[2][4];
    #pragma unroll
    for (int it = 0; it < 2; ++it)
        #pragma unroll
        for (int et = 0; et < 4; ++et) {
            acc[it][et][0]=0.f; acc[it][et][1]=0.f; acc[it][et][2]=0.f; acc[it][et][3]=0.f;
        }
    float s0acc[2] = {0.f, 0.f};
    float dmax = -3.0e38f;

    float4 ka0, ka1, va0, va1;

    auto issue_loads = [&](int s) {
        const float* ks = kb + (size_t)(64 * s + srow) * DIM + sd0;
        ka0 = *(const float4*)ks;
        ka1 = *(const float4*)(ks + 4);
        const float* vs = vb + (size_t)(64 * s + vrow) * DIM + ve0;
        va0 = *(const float4*)vs;
        va1 = *(const float4*)(vs + 4);
    };

    auto stage_write = [&](int buf) {
        // k -> f16 row-major
        union { fp16x2 h2[4]; short8 s8; } uk;
        uk.h2[0] = __builtin_amdgcn_cvt_pkrtz(ka0.x, ka0.y);
        uk.h2[1] = __builtin_amdgcn_cvt_pkrtz(ka0.z, ka0.w);
        uk.h2[2] = __builtin_amdgcn_cvt_pkrtz(ka1.x, ka1.y);
        uk.h2[3] = __builtin_amdgcn_cvt_pkrtz(ka1.z, ka1.w);
        *(short8*)&kL[buf][srow * PSTR + sd0] = uk.s8;
        // diag partial + 8-lane reduce
        float ds2 = ka0.x*ka0.x + ka0.y*ka0.y + ka0.z*ka0.z + ka0.w*ka0.w
                  + ka1.x*ka1.x + ka1.y*ka1.y + ka1.z*ka1.z + ka1.w*ka1.w;
        ds2 += __shfl_xor(ds2, 1);
        ds2 += __shfl_xor(ds2, 2);
        ds2 += __shfl_xor(ds2, 4);
        if ((l & 7) == 0) diagL[buf][srow] = ds2 * DIAGC;
        // v -> bf16 transposed [e][n]
        unsigned pv0 = cvt_pk_bf16(va0.x, va0.y);
        unsigned pv1 = cvt_pk_bf16(va0.z, va0.w);
        unsigned pv2 = cvt_pk_bf16(va1.x, va1.y);
        unsigned pv3 = cvt_pk_bf16(va1.z, va1.w);
        vT[buf][(ve0 + 0) * PSTR + vrow] = (short)(pv0 & 0xFFFF);
        vT[buf][(ve0 + 1) * PSTR + vrow] = (short)(pv0 >> 16);
        vT[buf][(ve0 + 2) * PSTR + vrow] = (short)(pv1 & 0xFFFF);
        vT[buf][(ve0 + 3) * PSTR + vrow] = (short)(pv1 >> 16);
        vT[buf][(ve0 + 4) * PSTR + vrow] = (short)(pv2 & 0xFFFF);
        vT[buf][(ve0 + 5) * PSTR + vrow] = (short)(pv2 >> 16);
        vT[buf][(ve0 + 6) * PSTR + vrow] = (short)(pv3 & 0xFFFF);
        vT[buf][(ve0 + 7) * PSTR + vrow] = (short)(pv3 >> 16);
    };

    // prologue: stage sub 0
    issue_loads(0);
    stage_write(0);
    __syncthreads();

    for (int s = 0; s < SUBS; ++s) {
        const int cur = s & 1;
        const bool more = (s + 1 < SUBS);
        if (more) issue_loads(s + 1);   // HBM latency hides under compute below

        // ---- GEMM1: dd = k @ (DNORM proj)^T ; epilogue -> epS (wave-private)
        #pragma unroll
        for (int nt = 0; nt < 4; ++nt) {
            const half8 a0 = *(const half8*)&kL[cur][(16 * nt + c) * PSTR + 8 * g];
            const half8 a1 = *(const half8*)&kL[cur][(16 * nt + c) * PSTR + 8 * g + 32];
            const float4 dg4 = *(const float4*)&diagL[cur][16 * nt + 4 * g];
            const float dgr[4] = {dg4.x, dg4.y, dg4.z, dg4.w};
            #pragma unroll
            for (int it = 0; it < 2; ++it) {
                if (it < nT) {
                    floatx4 d = {0.f, 0.f, 0.f, 0.f};
                    d = __builtin_amdgcn_mfma_f32_16x16x32_f16(a0, pj0[it], d, 0, 0, 0);
                    d = __builtin_amdgcn_mfma_f32_16x16x32_f16(a1, pj1[it], d, 0, 0, 0);
                    const bool t16 = (it == 1);
                    float ev[4];
                    #pragma unroll
                    for (int r = 0; r < 4; ++r) {
                        const float ddv = d[r];
                        if (!t16 || c < 10) dmax = fmaxf(dmax, ddv);
                        float e = __expf(ddv - dgr[r]);
                        if (t16 && c == 15) e = 1.0f;   // "ones" feature -> Vs in A0 row 271
                        s0acc[it] += e;
                        ev[r] = e;
                    }
                    uint2 pk;
                    pk.x = cvt_pk_bf16(ev[0], ev[1]);
                    pk.y = cvt_pk_bf16(ev[2], ev[3]);
                    *(uint2*)&epS[2 * w + it][c * PSTR + 16 * nt + 4 * g] = pk;
                }
            }
        }

        // ---- GEMM2: A0[e][f] += v^T @ ep   (contract n, bf16 16x16x32)
        #pragma unroll
        for (int ntp = 0; ntp < 2; ++ntp) {
            const short8 bq0 = *(const short8*)&epS[2 * w][c * PSTR + 32 * ntp + 8 * g];
            short8 bq1;
            if (nT == 2) bq1 = *(const short8*)&epS[2 * w + 1][c * PSTR + 32 * ntp + 8 * g];
            #pragma unroll
            for (int et = 0; et < 4; ++et) {
                const short8 av = *(const short8*)&vT[cur][(16 * et + c) * PSTR + 32 * ntp + 8 * g];
                acc[0][et] = __builtin_amdgcn_mfma_f32_16x16x32_bf16(av, bq0, acc[0][et], 0, 0, 0);
                if (nT == 2)
                    acc[1][et] = __builtin_amdgcn_mfma_f32_16x16x32_bf16(av, bq1, acc[1][et], 0, 0, 0);
            }
        }

        if (more) {
            stage_write(cur ^ 1);
            __syncthreads();
        }
    }

    // ---- epilogue: A0 partials [m][e] (lane holds e=16et+4g..+3 contiguous)
    {
        float* dst = A0p + (size_t)(bh * NCH + ch) * (MPAD * 64);
        #pragma unroll
        for (int it = 0; it < 2; ++it) {
            if (it < nT) {
                const int t = it ? 16 : t0;
                #pragma unroll
                for (int et = 0; et < 4; ++et)
                    *(floatx4*)&dst[(size_t)(16 * t + c) * 64 + 16 * et + 4 * g] = acc[it][et];
            }
        }
    }
    // ---- S0 atomics
    #pragma unroll
    for (int it = 0; it < 2; ++it) {
        if (it < nT) {
            const int t = it ? 16 : t0;
            float s = s0acc[it];
            s += __shfl_xor(s, 16);
            s += __shfl_xor(s, 32);
            if (g == 0 && (t < 16 || c < 10))
                atomicAdd(&S0p[bh * MPAD + 16 * t + c], s);
        }
    }
    // ---- dmax
    #pragma unroll
    for (int sft = 1; sft <= 32; sft <<= 1) dmax = fmaxf(dmax, __shfl_xor(dmax, sft));
    if (l == 0) atomicMax(gmax + bh, encf(dmax));
}

// ------------------------------------------------------------ reduce_ctx ----
// ctxT_ws[bh][e'][m] f16, e'=0..63 context cols, e'=64 k_cumsum; m padded to 288
__global__ __launch_bounds__(512, 1)
void reduce_ctx(const float* __restrict__ A0p, const float* __restrict__ S0p,
                const unsigned int* __restrict__ gmax, short* __restrict__ ctxw)
{
    __shared__ __align__(16) short L[65 * 288];
    const int bh = blockIdx.x, tid = threadIdx.x;
    const float emx = __expf(-decf(gmax[bh]));
    const int e = tid & 63, mi = tid >> 6;
    const float* base = A0p + (size_t)bh * NCH * MPAD * 64;
    float vs = 0.f;
    #pragma unroll
    for (int c2 = 0; c2 < NCH; ++c2)
        vs += base[(size_t)c2 * MPAD * 64 + (size_t)271 * 64 + e];   // "ones" row = Vs
    const float vsr = vs * KEPS;
    for (int m = mi; m < 288; m += 8) {
        float val = 0.f;
        if (m < MF) {
            float s = 0.f;
            #pragma unroll
            for (int c2 = 0; c2 < NCH; ++c2)
                s += base[(size_t)c2 * MPAD * 64 + (size_t)m * 64 + e];
            val = RATIO * (emx * s + vsr);
        }
        L[e * 288 + m] = f2h_bits(val);
    }
    for (int m = tid; m < 288; m += 512) {
        float val = 0.f;
        if (m < MF) val = RATIO * (emx * S0p[bh * MPAD + m] + KEPS * 4096.0f);
        L[64 * 288 + m] = f2h_bits(val);
    }
    __syncthreads();
    short* dst = ctxw + (size_t)bh * (65 * 288);
    for (int idx = tid; idx < 65 * 36; idx += 512)
        *(short8*)(dst + idx * 8) = *(const short8*)&L[idx * 8];
}

// ---------------------------------------------------------------- q_pass ----
// stage proj into LDS as f16(DNORM * proj), rows [272][PSTR]; rows >= 266 zeroed
__device__ __forceinline__ void stage_proj(short* projL, const float* __restrict__ proj, int tid) {
    for (int idx = tid; idx < 544; idx += 512) {
        const int f = idx >> 1, hf = idx & 1;
        short* dst = &projL[f * PSTR + hf * 32];
        if (f < MF) {
            const float* src = proj + f * 64 + hf * 32;
            #pragma unroll
            for (int j2 = 0; j2 < 8; ++j2) {
                float4 v4 = *(const float4*)(src + j2 * 4);
                short4s sv;
                sv[0] = f2h_bits(v4.x * DNORM);
                sv[1] = f2h_bits(v4.y * DNORM);
                sv[2] = f2h_bits(v4.z * DNORM);
                sv[3] = f2h_bits(v4.w * DNORM);
                *(short4s*)(dst + j2 * 4) = sv;
            }
        } else {
            short4s z; z[0] = 0; z[1] = 0; z[2] = 0; z[3] = 0;
            #pragma unroll
            for (int j2 = 0; j2 < 8; ++j2) *(short4s*)(dst + j2 * 4) = z;
        }
    }
}

__global__ __launch_bounds__(512, 2)
void q_pass(const float* __restrict__ qin, const float* __restrict__ proj,
            const short* __restrict__ ctxw, float* __restrict__ outp)
{
    __shared__ __align__(16) short projL[MPAD * PSTR];
    __shared__ __align__(16) short ctxL[65 * QSTR];    // ctxT[e'][m] f16

    const int tid = threadIdx.x;
    const int bh = blockIdx.x >> 5, rt = blockIdx.x & 31;
    const int c = tid & 15, g = (tid >> 4) & 3, w = tid >> 6;

    stage_proj(projL, proj, tid);
    {
        const short* src = ctxw + (size_t)bh * (65 * 288);
        for (int idx = tid; idx < 65 * 36; idx += 512) {
            const int r = idx / 36, s = idx - r * 36;
            *(short8*)&ctxL[r * QSTR + s * 8] = *(const short8*)(src + r * 288 + s * 8);
        }
    }
    // ---- load q B-frags (row R0 = rt*128 + 16w + c), diag
    half8 bf0, bf1;
    float dsum = 0.f;
    {
        const float* qs = qin + ((size_t)bh * NTOK + rt * 128 + 16 * w + c) * DIM;
        #pragma unroll
        for (int ksi = 0; ksi < 2; ++ksi) {
            const float* p4 = qs + ksi * 32 + 8 * g;
            float4 x0 = *(const float4*)p4;
            float4 x1 = *(const float4*)(p4 + 4);
            dsum += x0.x*x0.x + x0.y*x0.y + x0.z*x0.z + x0.w*x0.w
                  + x1.x*x1.x + x1.y*x1.y + x1.z*x1.z + x1.w*x1.w;
            half8& bf = ksi ? bf1 : bf0;
            bf[0]=(_Float16)x0.x; bf[1]=(_Float16)x0.y; bf[2]=(_Float16)x0.z; bf[3]=(_Float16)x0.w;
            bf[4]=(_Float16)x1.x; bf[5]=(_Float16)x1.y; bf[6]=(_Float16)x1.z; bf[7]=(_Float16)x1.w;
        }
    }
    float t1 = dsum + __shfl_xor(dsum, 16);
    const float diagc = (t1 + __shfl_xor(t1, 32)) * DIAGC;   // diag of own row c

    __syncthreads();   // proj + ctx ready

    // ---- GEMM1: dd^T = proj @ q^T : lane (c,g) holds dd[f=16t+4g+r2][row=c]
    floatx4 dd[17];
    #pragma unroll
    for (int t = 0; t < 17; ++t) {
        const short* ap = &projL[(16 * t + c) * PSTR + 8 * g];
        half8 a0 = *(const half8*)ap;
        half8 a1 = *(const half8*)(ap + 32);
        floatx4 d = {0.f, 0.f, 0.f, 0.f};
        d = __builtin_amdgcn_mfma_f32_16x16x32_f16(a0, bf0, d, 0, 0, 0);
        d = __builtin_amdgcn_mfma_f32_16x16x32_f16(a1, bf1, d, 0, 0, 0);
        dd[t] = d;
    }
    // ---- per-row max over valid f
    float mx = -3.0e38f;
    #pragma unroll
    for (int t = 0; t < 17; ++t) {
        #pragma unroll
        for (int r2 = 0; r2 < 4; ++r2) {
            const bool fval = (t < 16) || (4 * g + r2 < 10);
            if (fval) mx = fmaxf(mx, dd[t][r2]);
        }
    }
    mx = fmaxf(mx, __shfl_xor(mx, 16));
    mx = fmaxf(mx, __shfl_xor(mx, 32));

    // ---- qp in registers as 16x16x16 B-frags; denominator via VALU dot
    half4 bq[17];
    float denp = 0.f;
    #pragma unroll
    for (int t = 0; t < 17; ++t) {
        half4 b;
        #pragma unroll
        for (int r2 = 0; r2 < 4; ++r2) {
            float val = __expf(dd[t][r2] - diagc - mx) + KEPS;
            b[r2] = (_Float16)val;
            denp += val * h2f(ctxL[64 * QSTR + 16 * t + 4 * g + r2]);
        }
        bq[t] = b;
    }
    denp += __shfl_xor(denp, 16);
    denp += __shfl_xor(denp, 32);

    // ---- GEMM2: out^T[e'][r] = ctxT @ qp^T  (contract m, 17 K-steps of 16)
    floatx4 acc[4];
    #pragma unroll
    for (int i = 0; i < 4; ++i) { acc[i][0]=0.f; acc[i][1]=0.f; acc[i][2]=0.f; acc[i][3]=0.f; }
    #pragma unroll
    for (int e4 = 0; e4 < 4; ++e4) {
        #pragma unroll
        for (int t = 0; t < 17; ++t) {
            half4 a4 = *(const half4*)&ctxL[(16 * e4 + c) * QSTR + 16 * t + 4 * g];
            acc[e4] = __builtin_amdgcn_mfma_f32_16x16x16f16(a4, bq[t], acc[e4], 0, 0, 0);
        }
    }
    // ---- normalize + store: lane (c,g) holds out[row c][e' = 16e4+4g+r2]
    float den = (denp == 0.f) ? 1e-5f : denp;
    const float inv = 1.0f / den;
    float* ob = outp + ((size_t)bh * NTOK + rt * 128 + 16 * w + c) * DIM;
    #pragma unroll
    for (int e4 = 0; e4 < 4; ++e4) {
        float4 o = make_float4(acc[e4][0] * inv, acc[e4][1] * inv,
                               acc[e4][2] * inv, acc[e4][3] * inv);
        *(float4*)(ob + 16 * e4 + 4 * g) = o;
    }
}

extern "C" void kernel_launch(void* const* d_in, const int* in_sizes, int n_in,
                              void* d_out, int out_size, void* d_ws, size_t ws_size,
                              hipStream_t stream)
{
    const float* q    = (const float*)d_in[0];
    const float* k    = (const float*)d_in[1];
    const float* v    = (const float*)d_in[2];
    const float* proj = (const float*)d_in[3];
    float* out = (float*)d_out;
    float* ws  = (float*)d_ws;

    const size_t offS = (size_t)BH * NCH * MPAD * 64;   // A0p partials
    const size_t offG = offS + (size_t)BH * MPAD;       // S0p (atomic f32)
    const size_t offC = offG + 64;                      // gmax (encoded uint)

    float* A0p = ws;
    float* S0p = ws + offS;
    unsigned int* gmax = (unsigned int*)(ws + offG);
    short* ctxw = (short*)(ws + offC);

    // zero S0p + gmax (contiguous)
    (void)hipMemsetAsync(S0p, 0, ((size_t)BH * MPAD + 64) * sizeof(float), stream);
    hipLaunchKernelGGL(k_pass, dim3(BH * NCH * 2), dim3(512), 0, stream,
                       k, v, proj, A0p, S0p, gmax);
    hipLaunchKernelGGL(reduce_ctx, dim3(BH), dim3(512), 0, stream,
                       A0p, S0p, gmax, ctxw);
    hipLaunchKernelGGL(q_pass, dim3(BH * 32), dim3(512), 0, stream,
                       q, proj, ctxw, out);
}